// Round 16
// baseline (373.145 us; speedup 1.0000x reference)
//
#include <hip/hip_runtime.h>
#include <type_traits>

typedef unsigned short ushort;
typedef unsigned int uint;
typedef __bf16 bf16x8 __attribute__((ext_vector_type(8)));
typedef unsigned short ushort8v __attribute__((ext_vector_type(8)));
typedef float f32x4 __attribute__((ext_vector_type(4)));

__device__ __forceinline__ float b2f(ushort u) {
    unsigned int x = ((unsigned int)u) << 16;
    float f;
    __builtin_memcpy(&f, &x, 4);
    return f;
}
__device__ __forceinline__ ushort f2bf(float f) {
    unsigned int x;
    __builtin_memcpy(&x, &f, 4);
    unsigned int r = x + 0x7fffu + ((x >> 16) & 1u);
    return (ushort)(r >> 16);
}
__device__ __forceinline__ float u2f_lo(uint u) {
    uint x = u << 16;
    float f;
    __builtin_memcpy(&f, &x, 4);
    return f;
}
__device__ __forceinline__ float u2f_hi(uint u) {
    uint x = u & 0xffff0000u;
    float f;
    __builtin_memcpy(&f, &x, 4);
    return f;
}
__device__ __forceinline__ uint packbf(float a, float b) {
    return (uint)f2bf(a) | ((uint)f2bf(b) << 16);
}

#define NPIX 16384  // H*W = 128*128
#define PSTRIDE 136 // padded plane row stride (ushorts); 68 uints

// Channel-major tiled layout: [b][tile(256)][ch(CH)][64 px]
__device__ __forceinline__ size_t tadr(int b, int CH, int tile, int ch, int off) {
    return (((size_t)b * 256 + tile) * CH + ch) * 64 + off;
}
// Pixel-major tiled layout for x2: [b][tile(256)][px(64)][ch(128)]
__device__ __forceinline__ size_t padr(int b, int tile, int p, int c) {
    return (((size_t)b * 256 + tile) * 64 + p) * 128 + c;
}

// ---------------------------------------------------------------------------
// stage one 128x128 plane (channel c of ch-major tiled tensor) into padded LDS.
// ---------------------------------------------------------------------------
__device__ __forceinline__ void stage_plane(ushort* pl, const ushort* __restrict__ src,
                                            int b, int c, int CH, int tid) {
    uint* plu = (uint*)pl;
    for (int i = tid; i < 784; i += 256) {
        int idx;
        if (i < 136) idx = i;                       // rows 0-1
        else if (i < 272) idx = 8840 + (i - 136);   // rows 130-131
        else {
            int j = i - 272;
            int r = (j >> 2) + 2;                   // rows 2..129
            int cs = j & 3;
            idx = r * 68 + (cs == 0 ? 0 : 64 + cs); // uint 0 (left pad), 65-67 (right pad)
        }
        plu[idx] = 0u;
    }
    for (int i = tid; i < 2048; i += 256) {
        int row = i >> 4, xg = (i & 15) << 3;
        int px0 = row * 128 + xg;
        uint4 v = *(const uint4*)&src[tadr(b, CH, px0 >> 6, c, px0 & 63)];
        uint* dst = (uint*)&pl[(row + 2) * PSTRIDE + xg + 2];
        dst[0] = v.x; dst[1] = v.y; dst[2] = v.z; dst[3] = v.w;
    }
    __syncthreads();
}

// unpack 12 consecutive bf16 at rowp (16B-aligned) into f32
__device__ __forceinline__ void unpack12(const ushort* rowp, float* cc) {
    const uint* rp = (const uint*)rowp;
    uint4 u = *(const uint4*)rp;
    uint2 v = *(const uint2*)(rp + 4);
    cc[0] = u2f_lo(u.x); cc[1] = u2f_hi(u.x);
    cc[2] = u2f_lo(u.y); cc[3] = u2f_hi(u.y);
    cc[4] = u2f_lo(u.z); cc[5] = u2f_hi(u.z);
    cc[6] = u2f_lo(u.w); cc[7] = u2f_hi(u.w);
    cc[8] = u2f_lo(v.x); cc[9] = u2f_hi(v.x);
    cc[10] = u2f_lo(v.y); cc[11] = u2f_hi(v.y);
}

// unpack 24 consecutive bf16 at rowp (16B-aligned) into f32
__device__ __forceinline__ void unpack24(const ushort* rowp, float* cv) {
    const uint4* rp = (const uint4*)rowp;
    uint4 u0 = rp[0], u1 = rp[1], u2 = rp[2];
    cv[0] = u2f_lo(u0.x); cv[1] = u2f_hi(u0.x);
    cv[2] = u2f_lo(u0.y); cv[3] = u2f_hi(u0.y);
    cv[4] = u2f_lo(u0.z); cv[5] = u2f_hi(u0.z);
    cv[6] = u2f_lo(u0.w); cv[7] = u2f_hi(u0.w);
    cv[8] = u2f_lo(u1.x); cv[9] = u2f_hi(u1.x);
    cv[10] = u2f_lo(u1.y); cv[11] = u2f_hi(u1.y);
    cv[12] = u2f_lo(u1.z); cv[13] = u2f_hi(u1.z);
    cv[14] = u2f_lo(u1.w); cv[15] = u2f_hi(u1.w);
    cv[16] = u2f_lo(u2.x); cv[17] = u2f_hi(u2.x);
    cv[18] = u2f_lo(u2.y); cv[19] = u2f_hi(u2.y);
    cv[20] = u2f_lo(u2.z); cv[21] = u2f_hi(u2.z);
    cv[22] = u2f_lo(u2.w); cv[23] = u2f_hi(u2.w);
}

// ---------------------------------------------------------------------------
// K0: convert fp32 weights to bf16 once (qkv_w, pin_w, pout_w).
// ---------------------------------------------------------------------------
__global__ __launch_bounds__(256) void wcvt(const float* __restrict__ s0, ushort* __restrict__ d0, int n0,
                                            const float* __restrict__ s1, ushort* __restrict__ d1, int n1,
                                            const float* __restrict__ s2, ushort* __restrict__ d2, int n2) {
    int i = blockIdx.x * 256 + threadIdx.x;
    if (i < n0) d0[i] = f2bf(s0[i]);
    else if (i < n0 + n1) d1[i - n0] = f2bf(s1[i - n0]);
    else if (i < n0 + n1 + n2) d2[i - n0 - n1] = f2bf(s2[i - n0 - n1]);
}

// ---------------------------------------------------------------------------
// K1: fused LayerNorm(C=128) + qkv 1x1 conv via MFMA (unchanged from R15).
// ---------------------------------------------------------------------------
template <int O>
__global__ __launch_bounds__(256) void ln_gemm_mfma(const float* __restrict__ xin,
                                                    const ushort* __restrict__ Wb,
                                                    const float* __restrict__ gamma,
                                                    const float* __restrict__ beta,
                                                    ushort* __restrict__ out) {
    __shared__ ushort xs[64][136];
    __shared__ float red[2][4][64];
    __shared__ float mu[64], rs[64];
    __shared__ float gl[128], bl[128];

    const int blk = blockIdx.x;
    const int b = blk >> 8;
    const int tile = blk & 255;
    const int tid = threadIdx.x;

    const float* xb = xin + (size_t)b * 128 * NPIX + tile * 64;
    float vx[4][8];
#pragma unroll
    for (int k = 0; k < 4; k++) {
        int i = tid + k * 256;
        int p = i & 63, cg = i >> 6;
        const float* src = xb + (size_t)(cg * 8) * NPIX + p;
#pragma unroll
        for (int j = 0; j < 8; j++) vx[k][j] = src[(size_t)j * NPIX];
    }
    if (tid < 128) {
        gl[tid] = gamma[tid];
        bl[tid] = beta[tid];
    }
#pragma unroll
    for (int k = 0; k < 4; k++) {
        int i = tid + k * 256;
        int p = i & 63, cg = i >> 6;
        ushort8v u;
#pragma unroll
        for (int j = 0; j < 8; j++) u[j] = f2bf(vx[k][j]);
        *(ushort8v*)&xs[p][cg * 8] = u;
    }
    __syncthreads();

    {
        const int p = tid & 63, part = tid >> 6;
        float s = 0.f, ss = 0.f;
#pragma unroll
        for (int q = 0; q < 4; q++) {
            ushort8v u = *(const ushort8v*)&xs[p][part * 32 + q * 8];
#pragma unroll
            for (int j = 0; j < 8; j++) {
                float v = b2f(u[j]);
                s += v;
                ss += v * v;
            }
        }
        red[0][part][p] = s;
        red[1][part][p] = ss;
    }
    __syncthreads();
    if (tid < 64) {
        float s = red[0][0][tid] + red[0][1][tid] + red[0][2][tid] + red[0][3][tid];
        float ss = red[1][0][tid] + red[1][1][tid] + red[1][2][tid] + red[1][3][tid];
        float m = s * (1.f / 128.f);
        float var = ss * (1.f / 128.f) - m * m;
        mu[tid] = m;
        rs[tid] = rsqrtf(var + 1e-5f);
    }
    __syncthreads();
    {
        const int p = tid & 63, part = tid >> 6;
        const float mp = mu[p], rp = rs[p];
#pragma unroll
        for (int q = 0; q < 4; q++) {
            int c0 = part * 32 + q * 8;
            ushort8v u = *(const ushort8v*)&xs[p][c0];
            ushort8v o;
#pragma unroll
            for (int j = 0; j < 8; j++) {
                float v = b2f(u[j]);
                o[j] = f2bf((v - mp) * rp * gl[c0 + j] + bl[c0 + j]);
            }
            *(ushort8v*)&xs[p][c0] = o;
        }
    }
    __syncthreads();

    const int wv = tid >> 6, lane = tid & 63;
    const int lr = lane & 15, lg = lane >> 4;

    bf16x8 bfr[4][4];
#pragma unroll
    for (int t = 0; t < 4; t++)
#pragma unroll
        for (int kc = 0; kc < 4; kc++)
            bfr[t][kc] = __builtin_bit_cast(bf16x8, *(const ushort8v*)&xs[t * 16 + lr][kc * 32 + lg * 8]);

    constexpr int MT = O / 64;
    bf16x8 afp[2][4];
#pragma unroll
    for (int kc = 0; kc < 4; kc++)
        afp[0][kc] = __builtin_bit_cast(bf16x8,
            *(const ushort8v*)&Wb[(size_t)(wv * 16 + lr) * 128 + kc * 32 + lg * 8]);

    f32x4 accPair[2][4];
    const int px8 = tid & 7, cb = tid >> 3;
    ushort* outp = out + tadr(b, O, tile, 0, 0);

#pragma unroll
    for (int mt = 0; mt < MT; mt++) {
        if (mt + 1 < MT) {
            const int o0n = ((mt + 1) * 4 + wv) * 16;
#pragma unroll
            for (int kc = 0; kc < 4; kc++)
                afp[(mt + 1) & 1][kc] = __builtin_bit_cast(bf16x8,
                    *(const ushort8v*)&Wb[(size_t)(o0n + lr) * 128 + kc * 32 + lg * 8]);
        }
        f32x4* acc = accPair[mt & 1];
#pragma unroll
        for (int t = 0; t < 4; t++) acc[t] = (f32x4){0.f, 0.f, 0.f, 0.f};
#pragma unroll
        for (int kc = 0; kc < 4; kc++)
#pragma unroll
            for (int t = 0; t < 4; t++)
                acc[t] = __builtin_amdgcn_mfma_f32_16x16x32_bf16(afp[mt & 1][kc], bfr[t][kc], acc[t], 0, 0, 0);

        if (mt & 1) {
            __syncthreads();
#pragma unroll
            for (int h = 0; h < 2; h++) {
                const int lc = h * 64 + wv * 16 + lg * 4;
#pragma unroll
                for (int t = 0; t < 4; t++) {
                    int px = t * 16 + lr;
                    uint2 pk;
                    pk.x = packbf(accPair[h][t][0], accPair[h][t][1]);
                    pk.y = packbf(accPair[h][t][2], accPair[h][t][3]);
                    *(uint2*)&xs[px][lc] = pk;
                }
            }
            __syncthreads();
            const int pairbase = (mt >> 1) * 128;
#pragma unroll
            for (int cc = 0; cc < 4; cc++) {
                int c = cb + cc * 32;
                ushort8v u;
#pragma unroll
                for (int j = 0; j < 8; j++) u[j] = xs[px8 * 8 + j][c];
                *(ushort8v*)&outp[(size_t)(pairbase + c) * 64 + px8 * 8] = u;
            }
        }
    }
}

// ---------------------------------------------------------------------------
// K2: 3x3 depthwise conv, one (b,c) plane per block; ch-major tiled in/out.
// ---------------------------------------------------------------------------
__global__ __launch_bounds__(256) void dwconv3_lds(const ushort* __restrict__ in,
                                                   const float* __restrict__ wdw,
                                                   ushort* __restrict__ out, int CH) {
    __shared__ ushort pl[132 * PSTRIDE];
    const int c = blockIdx.x;
    const int b = blockIdx.y;
    const int tid = threadIdx.x;

    float w[9];
#pragma unroll
    for (int j = 0; j < 9; j++) w[j] = wdw[c * 9 + j];

    stage_plane(pl, in, b, c, CH, tid);

    const int x = (tid & 15) * 8;
    const int ybase = tid >> 4;
#pragma unroll 1
    for (int k = 0; k < 8; k++) {
        const int y = k * 16 + ybase;
        float a[8];
#pragma unroll
        for (int p = 0; p < 8; p++) a[p] = 0.f;
#pragma unroll
        for (int ky = 0; ky < 3; ky++) {
            float cc[12];
            unpack12(&pl[(y + ky + 1) * PSTRIDE + x], cc);
#pragma unroll
            for (int kx = 0; kx < 3; kx++) {
                float wv = w[ky * 3 + kx];
#pragma unroll
                for (int p = 0; p < 8; p++) a[p] += cc[p + kx + 1] * wv;
            }
        }
        const int px0 = (y << 7) + x;
        uint4 o;
        o.x = packbf(a[0], a[1]);
        o.y = packbf(a[2], a[3]);
        o.z = packbf(a[4], a[5]);
        o.w = packbf(a[6], a[7]);
        *(uint4*)&out[tadr(b, CH, px0 >> 6, c, px0 & 63)] = o;
    }
}

// ---------------------------------------------------------------------------
// K3: per (b,h) attention -> M (unchanged).
// ---------------------------------------------------------------------------
__global__ __launch_bounds__(512) void attn_M(const ushort* __restrict__ qkv,
                                              const float* __restrict__ temp,
                                              const float* __restrict__ attn_proj,
                                              ushort* __restrict__ M) {
    __shared__ float Sp[8][16][16];
    __shared__ float QSS[8][16], KSS[8][16];
    __shared__ float A[16][17];

    const int bh = blockIdx.x, b = bh >> 3, h = bh & 7;
    const int tid = threadIdx.x;
    const int w = tid >> 6, lane = tid & 63;
    const int lr = lane & 15, lg = lane >> 4;

    const size_t qbase = (((size_t)b * 256 + w * 32) * 384 + h * 16 + lr) * 64 + lg * 8;
    const size_t kbase = qbase + (size_t)128 * 64;

    f32x4 acc = {0.f, 0.f, 0.f, 0.f};
    f32x4 accq = {0.f, 0.f, 0.f, 0.f};
    f32x4 acck = {0.f, 0.f, 0.f, 0.f};
#pragma unroll 2
    for (int it = 0; it < 64; it++) {
        size_t off = (size_t)(it >> 1) * (384 * 64) + (it & 1) * 32;
        bf16x8 qf = __builtin_bit_cast(bf16x8, *(const ushort8v*)(qkv + qbase + off));
        bf16x8 kf = __builtin_bit_cast(bf16x8, *(const ushort8v*)(qkv + kbase + off));
        acc = __builtin_amdgcn_mfma_f32_16x16x32_bf16(qf, kf, acc, 0, 0, 0);
        accq = __builtin_amdgcn_mfma_f32_16x16x32_bf16(qf, qf, accq, 0, 0, 0);
        acck = __builtin_amdgcn_mfma_f32_16x16x32_bf16(kf, kf, acck, 0, 0, 0);
    }
#pragma unroll
    for (int r = 0; r < 4; r++) Sp[w][lg * 4 + r][lr] = acc[r];
    if (lg == (lr >> 2)) {
        QSS[w][lr] = accq[lr & 3];
        KSS[w][lr] = acck[lr & 3];
    }
    __syncthreads();

    if (tid < 256) {
        const int d = tid >> 4, e = tid & 15;
        float S = 0.f, q2 = 0.f, k2 = 0.f;
#pragma unroll
        for (int s = 0; s < 8; s++) {
            S += Sp[s][d][e];
            q2 += QSS[s][d];
            k2 += KSS[s][e];
        }
        float nq = fmaxf(sqrtf(q2), 1e-12f);
        float nk = fmaxf(sqrtf(k2), 1e-12f);
        float logit = S / (nq * nk) * temp[h];
        float m = logit;
        for (int off = 8; off; off >>= 1) m = fmaxf(m, __shfl_xor(m, off, 64));
        float ex = expf(logit - m);
        float sum = ex;
        for (int off = 8; off; off >>= 1) sum += __shfl_xor(sum, off, 64);
        A[d][e] = ex / sum;
    }
    __syncthreads();

    for (int i = tid; i < 2048; i += 512) {
        int o = i >> 4, ee = i & 15;
        float acc2 = 0.f;
#pragma unroll
        for (int dd = 0; dd < 16; dd++) acc2 += attn_proj[o * 128 + h * 16 + dd] * A[dd][ee];
        M[((size_t)b * 128 + o) * 128 + h * 16 + ee] = f2bf(acc2);
    }
}

// ---------------------------------------------------------------------------
// K4+K5 FUSED: x2 = x + M_b @ v, then t = pin @ LN2(x2) (unchanged).
// ---------------------------------------------------------------------------
__global__ __launch_bounds__(256) void mv_ln_mfma(const ushort* __restrict__ qkv,
                                                  const ushort* __restrict__ Mb16,
                                                  const float* __restrict__ x,
                                                  const ushort* __restrict__ pin_b,
                                                  const float* __restrict__ gamma,
                                                  const float* __restrict__ beta,
                                                  ushort* __restrict__ x2,
                                                  ushort* __restrict__ t_out) {
    __shared__ ushort ts[64][136];
    __shared__ float red[2][4][64];
    __shared__ float mu[64], rs[64];
    __shared__ float gl[128], bl[128];

    const int blk = blockIdx.x;
    const int b = blk >> 8;
    const int tile = blk & 255;
    const int tid = threadIdx.x;
    const int wv = tid >> 6, lane = tid & 63;
    const int lr = lane & 15, lg = lane >> 4;

    const ushort* Mb = Mb16 + (size_t)b * 128 * 128;
    bf16x8 mfr[2][4];
#pragma unroll
    for (int mt = 0; mt < 2; mt++)
#pragma unroll
        for (int kc = 0; kc < 4; kc++)
            mfr[mt][kc] = __builtin_bit_cast(bf16x8,
                *(const ushort8v*)&Mb[(size_t)((wv * 2 + mt) * 16 + lr) * 128 + kc * 32 + lg * 8]);

    const ushort* vb = qkv + tadr(b, 384, tile, 256, 0);
    ushort8v vv[4];
#pragma unroll
    for (int k = 0; k < 4; k++) {
        int idx = tid + k * 256;
        int c = idx & 127, pg = idx >> 7;
        vv[k] = *(const ushort8v*)&vb[c * 64 + pg * 8];
    }
    if (tid < 128) {
        gl[tid] = gamma[tid];
        bl[tid] = beta[tid];
    }
#pragma unroll
    for (int k = 0; k < 4; k++) {
        int idx = tid + k * 256;
        int c = idx & 127, pg = idx >> 7;
#pragma unroll
        for (int j = 0; j < 8; j++) ts[pg * 8 + j][c] = vv[k][j];
    }
    __syncthreads();

    bf16x8 bfr[4][4];
#pragma unroll
    for (int t = 0; t < 4; t++)
#pragma unroll
        for (int kc = 0; kc < 4; kc++)
            bfr[t][kc] = __builtin_bit_cast(bf16x8, *(const ushort8v*)&ts[t * 16 + lr][kc * 32 + lg * 8]);
    __syncthreads();

#pragma unroll
    for (int mt = 0; mt < 2; mt++) {
        const int o0 = (wv * 2 + mt) * 16;
        f32x4 acc[4] = {{0.f, 0.f, 0.f, 0.f}, {0.f, 0.f, 0.f, 0.f}, {0.f, 0.f, 0.f, 0.f}, {0.f, 0.f, 0.f, 0.f}};
#pragma unroll
        for (int kc = 0; kc < 4; kc++)
#pragma unroll
            for (int t = 0; t < 4; t++)
                acc[t] = __builtin_amdgcn_mfma_f32_16x16x32_bf16(mfr[mt][kc], bfr[t][kc], acc[t], 0, 0, 0);
#pragma unroll
        for (int t = 0; t < 4; t++) {
            int px = t * 16 + lr;
            const float* xp = &x[((size_t)b * 128 + o0 + lg * 4) * NPIX + tile * 64 + px];
            uint2 pk;
            pk.x = packbf(xp[0] + acc[t][0], xp[NPIX] + acc[t][1]);
            pk.y = packbf(xp[2 * NPIX] + acc[t][2], xp[3 * NPIX] + acc[t][3]);
            *(uint2*)&ts[px][o0 + lg * 4] = pk;
        }
    }

    bf16x8 pfp[2][4];
#pragma unroll
    for (int kc = 0; kc < 4; kc++)
        pfp[0][kc] = __builtin_bit_cast(bf16x8,
            *(const ushort8v*)&pin_b[(size_t)(wv * 16 + lr) * 128 + kc * 32 + lg * 8]);
    __syncthreads();

#pragma unroll
    for (int k = 0; k < 4; k++) {
        int idx = tid + k * 256;
        int p = idx >> 4, seg = idx & 15;
        uint4 v = *(const uint4*)&ts[p][seg * 8];
        *(uint4*)&x2[padr(b, tile, p, seg * 8)] = v;
    }
    {
        const int p = tid & 63, part = tid >> 6;
        float s = 0.f, ss = 0.f;
#pragma unroll
        for (int q = 0; q < 4; q++) {
            ushort8v u = *(const ushort8v*)&ts[p][part * 32 + q * 8];
#pragma unroll
            for (int j = 0; j < 8; j++) {
                float v = b2f(u[j]);
                s += v;
                ss += v * v;
            }
        }
        red[0][part][p] = s;
        red[1][part][p] = ss;
    }
    __syncthreads();
    if (tid < 64) {
        float s = red[0][0][tid] + red[0][1][tid] + red[0][2][tid] + red[0][3][tid];
        float ss = red[1][0][tid] + red[1][1][tid] + red[1][2][tid] + red[1][3][tid];
        float m = s * (1.f / 128.f);
        float var = ss * (1.f / 128.f) - m * m;
        mu[tid] = m;
        rs[tid] = rsqrtf(var + 1e-5f);
    }
    __syncthreads();
    {
        const int p = tid & 63, part = tid >> 6;
        const float mp = mu[p], rp = rs[p];
#pragma unroll
        for (int q = 0; q < 4; q++) {
            int c0 = part * 32 + q * 8;
            ushort8v u = *(const ushort8v*)&ts[p][c0];
            ushort8v o;
#pragma unroll
            for (int j = 0; j < 8; j++) {
                float v = b2f(u[j]);
                o[j] = f2bf((v - mp) * rp * gl[c0 + j] + bl[c0 + j]);
            }
            *(ushort8v*)&ts[p][c0] = o;
        }
    }
    __syncthreads();

    bf16x8 bfr2[4][4];
#pragma unroll
    for (int t = 0; t < 4; t++)
#pragma unroll
        for (int kc = 0; kc < 4; kc++)
            bfr2[t][kc] = __builtin_bit_cast(bf16x8, *(const ushort8v*)&ts[t * 16 + lr][kc * 32 + lg * 8]);

    f32x4 accPair[2][4];
    const int px8 = tid & 7, cb = tid >> 3;
    ushort* toutp = t_out + tadr(b, 256, tile, 0, 0);

#pragma unroll
    for (int mt = 0; mt < 4; mt++) {
        if (mt + 1 < 4) {
            const int o0n = ((mt + 1) * 4 + wv) * 16;
#pragma unroll
            for (int kc = 0; kc < 4; kc++)
                pfp[(mt + 1) & 1][kc] = __builtin_bit_cast(bf16x8,
                    *(const ushort8v*)&pin_b[(size_t)(o0n + lr) * 128 + kc * 32 + lg * 8]);
        }
        f32x4* acc = accPair[mt & 1];
#pragma unroll
        for (int t = 0; t < 4; t++) acc[t] = (f32x4){0.f, 0.f, 0.f, 0.f};
#pragma unroll
        for (int kc = 0; kc < 4; kc++)
#pragma unroll
            for (int t = 0; t < 4; t++)
                acc[t] = __builtin_amdgcn_mfma_f32_16x16x32_bf16(pfp[mt & 1][kc], bfr2[t][kc], acc[t], 0, 0, 0);

        if (mt & 1) {
            __syncthreads();
#pragma unroll
            for (int h = 0; h < 2; h++) {
                const int lc = h * 64 + wv * 16 + lg * 4;
#pragma unroll
                for (int t = 0; t < 4; t++) {
                    int px = t * 16 + lr;
                    uint2 pk;
                    pk.x = packbf(accPair[h][t][0], accPair[h][t][1]);
                    pk.y = packbf(accPair[h][t][2], accPair[h][t][3]);
                    *(uint2*)&ts[px][lc] = pk;
                }
            }
            __syncthreads();
            const int pairbase = (mt >> 1) * 128;
#pragma unroll
            for (int cc = 0; cc < 4; cc++) {
                int c = cb + cc * 32;
                ushort8v u;
#pragma unroll
                for (int j = 0; j < 8; j++) u[j] = ts[px8 * 8 + j][c];
                *(ushort8v*)&toutp[(size_t)(pairbase + c) * 64 + px8 * 8] = u;
            }
        }
    }
}

// ---------------------------------------------------------------------------
// K6+K7+K8 FULLY FUSED: per 64-px tile, for each 64-channel chunk of t:
// stage 5-row halo -> conv3/conv5/gelu in registers -> gated chunk written
// directly into tr_read LDS layout [half][pxq][c][pxl] -> MFMA accumulate.
// Kills the 268MB gated global round-trip; VALU(conv) overlaps MFMA across
// waves/blocks. Bijective chunked XCD swizzle keeps halo rows L2-local.
// ---------------------------------------------------------------------------
__global__ __launch_bounds__(256) void dw_gdfn_fused(const ushort* __restrict__ t,
                                                     const float* __restrict__ w3_,
                                                     const float* __restrict__ w5_,
                                                     const float* __restrict__ c1w,
                                                     const ushort* __restrict__ x2,
                                                     const ushort* __restrict__ pout_b,
                                                     float* __restrict__ out) {
    __shared__ union {
        ushort th[64][5][72];  // 46080 B: halo tile for one 64-ch chunk
        float xf[32][129];     // 16512 B: f32 repack (epilogue only)
    } smA;
    __shared__ ushort tb[2][4][1040];  // 16640 B: gated chunk, tr_read layout

    // bijective XCD-chunked swizzle: 2048 = 8 XCDs x 256 tiles (one image each)
    const int blk0 = blockIdx.x;
    const int wg = (blk0 & 7) * 256 + (blk0 >> 3);
    const int b = wg >> 8, tile = wg & 255;
    const int y = tile >> 1, h = tile & 1;
    const int tid = threadIdx.x;
    const int wv = tid >> 6, lane = tid & 63;
    const int lr = lane & 15, lg = lane >> 4;
    const int ci = tid >> 2, g = tid & 3;  // compute map: channel-local, px group

    const uint lbase = (uint)(uintptr_t)&tb[0][0][0] + lg * 256 + lr * 2;

    f32x4 acc[2][4];
#pragma unroll
    for (int mt = 0; mt < 2; mt++)
#pragma unroll
        for (int tt = 0; tt < 4; tt++) acc[mt][tt] = (f32x4){0.f, 0.f, 0.f, 0.f};

#pragma unroll 1
    for (int cc = 0; cc < 4; cc++) {
        __syncthreads();  // prev chunk's th reads + tb reads done
        // ---- stage halo: 64 ch x 5 rows x [2 pad | 64 px | 2 pad | 4 junk->0]
        for (int i = tid; i < 320; i += 256) {
            int sci = i & 63, r = i >> 6;
            int yr = y + r - 2;
            ushort* dst = &smA.th[sci][r][0];
            uint* d4 = (uint*)dst;
            if (yr < 0 || yr > 127) {
                uint4 z = {0u, 0u, 0u, 0u};
#pragma unroll
                for (int k = 0; k < 9; k++) ((uint4*)dst)[k] = z;
            } else {
                int c = cc * 64 + sci;
                const ushort* rowc = t + tadr(b, 256, yr * 2 + h, c, 0);
                d4[0] = (h == 0) ? 0u : *(const uint*)(t + tadr(b, 256, yr * 2, c, 62));
#pragma unroll
                for (int k = 0; k < 8; k++) {
                    uint4 v = *(const uint4*)&rowc[k * 8];
                    d4[1 + k * 4] = v.x; d4[2 + k * 4] = v.y;
                    d4[3 + k * 4] = v.z; d4[4 + k * 4] = v.w;
                }
                d4[33] = (h == 1) ? 0u : *(const uint*)(t + tadr(b, 256, yr * 2 + 1, c, 0));
                d4[34] = 0u; d4[35] = 0u;
            }
        }
        __syncthreads();
        // ---- conv3/conv5/gelu: thread = (channel ci, px group g of 16)
        {
            const int c = cc * 64 + ci;
            float w5r[25], w3r[9];
#pragma unroll
            for (int j = 0; j < 25; j++) w5r[j] = w5_[c * 25 + j];
#pragma unroll
            for (int j = 0; j < 9; j++) w3r[j] = w3_[c * 9 + j];
            const float c1v = c1w[c];
            float a5[16], a3[16], tcv[16];
#pragma unroll
            for (int j = 0; j < 16; j++) { a5[j] = 0.f; a3[j] = 0.f; }
#pragma unroll
            for (int r = 0; r < 5; r++) {
                float cv[24];
                unpack24(&smA.th[ci][r][g * 16], cv);
#pragma unroll
                for (int kx = 0; kx < 5; kx++) {
                    float w = w5r[r * 5 + kx];
#pragma unroll
                    for (int j = 0; j < 16; j++) a5[j] += cv[j + kx] * w;
                }
                if (r >= 1 && r <= 3) {
#pragma unroll
                    for (int kx = 0; kx < 3; kx++) {
                        float w = w3r[(r - 1) * 3 + kx];
#pragma unroll
                        for (int j = 0; j < 16; j++) a3[j] += cv[j + 1 + kx] * w;
                    }
                }
                if (r == 2) {
#pragma unroll
                    for (int j = 0; j < 16; j++) tcv[j] = cv[j + 2];
                }
            }
            ushort8v o3a, o3b, o5a, o5b;
#pragma unroll
            for (int j = 0; j < 16; j++) {
                float x1 = tcv[j] * c1v;
                float gg = x1 * __builtin_amdgcn_rcpf(1.f + __expf(-1.702f * x1));
                ushort v3 = f2bf(gg * a3[j]);
                ushort v5 = f2bf(gg * a5[j]);
                if (j < 8) { o3a[j] = v3; o5a[j] = v5; }
                else { o3b[j - 8] = v3; o5b[j - 8] = v5; }
            }
            *(ushort8v*)&tb[0][g][ci * 16] = o3a;
            *(ushort8v*)&tb[0][g][ci * 16 + 8] = o3b;
            *(ushort8v*)&tb[1][g][ci * 16] = o5a;
            *(ushort8v*)&tb[1][g][ci * 16 + 8] = o5b;
        }
        __syncthreads();
        // ---- MFMA over both k-halves (dw3: k=cc*64.., dw5: k=256+cc*64..)
#pragma unroll
        for (int hh = 0; hh < 2; hh++) {
            bf16x8 bfrg[4][2];
            const uint la = lbase + hh * 8320;
#pragma unroll
            for (int tt = 0; tt < 4; tt++)
#pragma unroll
                for (int kc = 0; kc < 2; kc++) {
                    uint2 r0, r1;
                    asm volatile("ds_read_b64_tr_b16 %0, %2 offset:%3\n\t"
                                 "ds_read_b64_tr_b16 %1, %2 offset:%4"
                                 : "=&v"(r0), "=&v"(r1)
                                 : "v"(la), "i"(tt * 2080 + kc * 1024), "i"(tt * 2080 + kc * 1024 + 128));
                    uint4 q;
                    q.x = r0.x; q.y = r0.y; q.z = r1.x; q.w = r1.y;
                    bfrg[tt][kc] = __builtin_bit_cast(bf16x8, q);
                }
            asm volatile("s_waitcnt lgkmcnt(0)" ::: "memory");
            __builtin_amdgcn_sched_barrier(0);

#pragma unroll
            for (int mt = 0; mt < 2; mt++) {
                const int o0 = (wv * 2 + mt) * 16;
                bf16x8 afr[2];
#pragma unroll
                for (int kc = 0; kc < 2; kc++)
                    afr[kc] = __builtin_bit_cast(bf16x8,
                        *(const ushort8v*)&pout_b[(size_t)(o0 + lr) * 512 + hh * 256 + cc * 64 + kc * 32 + lg * 8]);
#pragma unroll
                for (int kc = 0; kc < 2; kc++)
#pragma unroll
                    for (int tt = 0; tt < 4; tt++)
                        acc[mt][tt] = __builtin_amdgcn_mfma_f32_16x16x32_bf16(afr[kc], bfrg[tt][kc], acc[mt][tt], 0, 0, 0);
            }
        }
    }
    __syncthreads();

    // epilogue: add x2, repack via xf[32][129] in two 32-px halves
#pragma unroll
    for (int hf = 0; hf < 2; hf++) {
#pragma unroll
        for (int mt = 0; mt < 2; mt++)
#pragma unroll
            for (int t2 = 0; t2 < 2; t2++) {
                const int tt = hf * 2 + t2;
                int o0 = (wv * 2 + mt) * 16 + lg * 4;
                int px = tt * 16 + lr;
                uint2 xw = *(const uint2*)&x2[padr(b, tile, px, o0)];
                smA.xf[px - hf * 32][o0 + 0] = u2f_lo(xw.x) + acc[mt][tt][0];
                smA.xf[px - hf * 32][o0 + 1] = u2f_hi(xw.x) + acc[mt][tt][1];
                smA.xf[px - hf * 32][o0 + 2] = u2f_lo(xw.y) + acc[mt][tt][2];
                smA.xf[px - hf * 32][o0 + 3] = u2f_hi(xw.y) + acc[mt][tt][3];
            }
        __syncthreads();
        {
            const int qx = tid & 7;
            const int cbase = tid >> 3;
#pragma unroll
            for (int cc2 = 0; cc2 < 4; cc2++) {
                int c = cbase + cc2 * 32;
                float4 v;
                v.x = smA.xf[qx * 4 + 0][c];
                v.y = smA.xf[qx * 4 + 1][c];
                v.z = smA.xf[qx * 4 + 2][c];
                v.w = smA.xf[qx * 4 + 3][c];
                *(float4*)&out[((size_t)b * 128 + c) * NPIX + tile * 64 + hf * 32 + qx * 4] = v;
            }
        }
        __syncthreads();
    }
}

// ---------------------------------------------------------------------------
extern "C" void kernel_launch(void* const* d_in, const int* in_sizes, int n_in,
                              void* d_out, int out_size, void* d_ws, size_t ws_size,
                              hipStream_t stream) {
    const float* x = (const float*)d_in[0];
    const float* ln1_w = (const float*)d_in[1];
    const float* ln1_b = (const float*)d_in[2];
    const float* qkv_w = (const float*)d_in[3];
    const float* qkv_dw = (const float*)d_in[4];
    const float* temperature = (const float*)d_in[5];
    const float* attn_proj = (const float*)d_in[6];
    const float* ln2_w = (const float*)d_in[7];
    const float* ln2_b = (const float*)d_in[8];
    const float* pin_w = (const float*)d_in[9];
    const float* c1_w = (const float*)d_in[10];
    const float* c3_w = (const float*)d_in[11];
    const float* c5_w = (const float*)d_in[12];
    const float* pout_w = (const float*)d_in[13];
    float* out = (float*)d_out;

    char* ws = (char*)d_ws;
    ushort* qkv_pre = (ushort*)(ws + 0);            // 100,663,296 (dead after dwconv3)
    ushort* qkv     = (ushort*)(ws + 100663296);    // 100,663,296 (dead after mv_ln)
    ushort* x2      = (ushort*)(ws + 201326592);    //  33,554,432 px-major (lives to end)
    ushort* t       = (ushort*)(ws + 0);            //  67,108,864 (reuses qkv_pre)
    ushort* Mb16    = (ushort*)(ws + 235151360);    //    262,144
    ushort* qkv_wb  = (ushort*)(ws + 235413504);    //     98,304
    ushort* pin_wb  = (ushort*)(ws + 235511808);    //     65,536
    ushort* pout_wb = (ushort*)(ws + 235577344);    //    131,072  (end ~235.7 MB)

    // K0: weight conversion (f32 -> bf16)
    wcvt<<<576, 256, 0, stream>>>(qkv_w, qkv_wb, 49152, pin_w, pin_wb, 32768, pout_w, pout_wb, 65536);
    // K1: qkv_pre = qkv_w @ LN1(x)
    ln_gemm_mfma<384><<<2048, 256, 0, stream>>>(x, qkv_wb, ln1_w, ln1_b, qkv_pre);
    // K2: qkv = dwconv3x3(qkv_pre)
    dwconv3_lds<<<dim3(384, 8), 256, 0, stream>>>(qkv_pre, qkv_dw, qkv, 384);
    // K3: attention (norms + QK^T + softmax + attn_proj fold)
    attn_M<<<64, 512, 0, stream>>>(qkv, temperature, attn_proj, Mb16);
    // K4+K5 fused: x2 = x + M_b @ v ; t = pin @ LN2(x2)
    mv_ln_mfma<<<2048, 256, 0, stream>>>(qkv, Mb16, x, pin_wb, ln2_w, ln2_b, x2, t);
    // K6+K7+K8 fully fused: out = x2 + pout @ [gelu(t*c1)*dw3(t); gelu(t*c1)*dw5(t)]
    dw_gdfn_fused<<<2048, 256, 0, stream>>>(t, c3_w, c5_w, c1_w, x2, pout_wb, out);
}